// Round 2
// baseline (229.124 us; speedup 1.0000x reference)
//
#include <hip/hip_runtime.h>
#include <math.h>

// RotaryEmbedding: x (4,16,8192,64) fp32. Rotate first ROTATE=4 pairs
// (elements 0..7) of last dim; copy elements 8..63 through.
//
// R1 lesson: doing tanhf/cosf/sinf inside the hot kernel serialized every
// wave on masked transcendental code (8/64 lanes active, but the whole wave
// pays) -> 1.2 TB/s. There are only 4 distinct (c,s) pairs for the entire
// tensor, so precompute them in a tiny kernel into d_ws and make the hot
// kernel a pure copy + 8 FMAs on the rotating lanes.

#define DIM 64
#define F4_PER_ROW (DIM / 4)   // 16
#define ROTATE 4

// ws layout: ws[0..3] = cos(theta_k), ws[4..7] = sin(theta_k)
__global__ void rope_precompute(const float* __restrict__ dparam,
                                const float* __restrict__ thetas,
                                float* __restrict__ ws)
{
    int k = threadIdx.x;
    if (k < ROTATE) {
        float direction = tanhf(dparam[0] * 0.5f);  // sigmoid(d)*2-1
        float t = direction * thetas[k];
        ws[k]          = cosf(t);
        ws[k + ROTATE] = sinf(t);
    }
}

__global__ __launch_bounds__(256) void rope_kernel(
    const float4* __restrict__ x,
    const float* __restrict__ cs,   // d_ws: 4 cos + 4 sin
    float4* __restrict__ out,
    int n4)
{
    int idx = blockIdx.x * blockDim.x + threadIdx.x;
    if (idx >= n4) return;

    float4 v = x[idx];
    int pos = idx & (F4_PER_ROW - 1);   // position within the 64-float row

    if (pos < 2) {
        int p0 = pos * 2;               // first pair index in this float4
        float c0 = cs[p0],     c1 = cs[p0 + 1];
        float s0 = cs[p0 + 4], s1 = cs[p0 + 5];
        float xi0 = v.x, xj0 = v.y;
        float xi1 = v.z, xj1 = v.w;
        v.x = fmaf(xi0, c0,  xj0 * s0);
        v.y = fmaf(xj0, c0, -xi0 * s0);
        v.z = fmaf(xi1, c1,  xj1 * s1);
        v.w = fmaf(xj1, c1, -xi1 * s1);
    }

    out[idx] = v;
}

extern "C" void kernel_launch(void* const* d_in, const int* in_sizes, int n_in,
                              void* d_out, int out_size, void* d_ws, size_t ws_size,
                              hipStream_t stream)
{
    const float* x      = (const float*)d_in[0];
    const float* dparam = (const float*)d_in[1];
    const float* thetas = (const float*)d_in[2];
    float* out          = (float*)d_out;
    float* ws           = (float*)d_ws;

    int n  = in_sizes[0];        // 33,554,432
    int n4 = n / 4;              // 8,388,608 float4s

    rope_precompute<<<1, 64, 0, stream>>>(dparam, thetas, ws);

    const int block = 256;
    int grid = (n4 + block - 1) / block;
    rope_kernel<<<grid, block, 0, stream>>>(
        (const float4*)x, ws, (float4*)out, n4);
}